// Round 7
// baseline (193.840 us; speedup 1.0000x reference)
//
#include <hip/hip_runtime.h>
#include <math.h>

// Capsule dynamic routing, fully fused, 2-BATCH BLOCKED, TPB=1024: one block
// per (c, batch-pair). B=256, C=10, N=1152, Din=8, U=16, 3 iters.
//
// Round-7. Round-6 killed the spill (WRITE 95MB -> 160KB) but sat at 22%
// occupancy: ~200 actual VGPRs -> 1 block/CU -> 2 waves/SIMD, latency-bound
// (VALUBusy 24%, dur ~90us ~= round-0 despite halved L2 W-traffic).
// Fix: TPB=1024. Per-thread u_hat is layout-invariant (2*1152*16/TPB floats),
// so 1024 threads -> 36 floats/thread (8 threads per n, 2 u each). Live set
// ~80 regs << 128, and a 1024-thread block FORCES alloc <= 128 (4 waves/SIMD
// must co-reside) -> 16 waves/CU resident = 50% occupancy, 2x latency hiding,
// with a hard compiler cap that has real headroom (no round-2-style gamble).
//  * u_hat in 18 NAMED float2 regs; W read as float2 (8 lanes cover a row).
//  * b logits in LDS; x direct from global (8-lane broadcast, L2-resident).
//  * iteration 0 peeled (softmax(ones)=1/1152). exp overcount now 8x.
//  * reductions: p over gg-lanes (masks 8/16/32); b-update over u-lanes
//    (masks 1/2/4); 16 wave-partials in LDS.

#define BATCH 256
#define CAPS  10
#define NIN   1152
#define DIN   8
#define UDIM  16
#define TPB   1024

__global__ __launch_bounds__(TPB, 1) void capsule_routing_kernel(
    const float* __restrict__ x,   // (B, N, Din)
    const float* __restrict__ W,   // (C, N, Din, U)
    float* __restrict__ out)       // (B, C, U)
{
    const int gblk = blockIdx.x;      // c-major for L2 W-locality
    const int c    = gblk >> 7;       // 0..9
    const int bp   = gblk & 127;      // 0..127  (batch pair)
    const int b0   = bp << 1;
    const int t    = threadIdx.x;     // 0..1023
    const int u2   = (t & 7) << 1;    // u base: 0,2,..,14 (2 comps/thread)
    const int gg   = t >> 3;          // 0..127 (n residue)
    const int wave = t >> 6;          // 0..15

    __shared__ float b_s[2][NIN];       // routing logits, per batch (9.2 KB)
    __shared__ float redB[2][16];       // per-wave exp-sum partials
    __shared__ float ps[2][16][UDIM];   // per-wave partial s
    __shared__ float v_s[2][UDIM];      // squashed output

    const float* Wc = W + (size_t)c * (NIN * DIN * UDIM);
    const float* xA = x + (size_t)b0 * (NIN * DIN);
    const float* xB = xA + (NIN * DIN);

    // u_hat in 18 NAMED float2 registers (array form spills)
    float2 uA0,uA1,uA2,uA3,uA4,uA5,uA6,uA7,uA8;
    float2 uB0,uB1,uB2,uB3,uB4,uB5,uB6,uB7,uB8;

    // W row stride per din = 16 floats = 8 float2; thread's column = u2.
#define UHC(K, DA, DB) { \
    const int n_ = gg + 128 * (K); \
    const float2* wr_ = (const float2*)(Wc + n_ * (DIN * UDIM) + u2); \
    float2 a_, d_; \
    { /* din 0..3 */ \
        const float4 xa_ = ((const float4*)(xA + n_ * DIN))[0]; \
        const float4 ya_ = ((const float4*)(xB + n_ * DIN))[0]; \
        const float2 w0_ = wr_[0], w1_ = wr_[8], w2_ = wr_[16], w3_ = wr_[24]; \
        a_.x = xa_.x*w0_.x + xa_.y*w1_.x + xa_.z*w2_.x + xa_.w*w3_.x; \
        a_.y = xa_.x*w0_.y + xa_.y*w1_.y + xa_.z*w2_.y + xa_.w*w3_.y; \
        d_.x = ya_.x*w0_.x + ya_.y*w1_.x + ya_.z*w2_.x + ya_.w*w3_.x; \
        d_.y = ya_.x*w0_.y + ya_.y*w1_.y + ya_.z*w2_.y + ya_.w*w3_.y; \
    } \
    __builtin_amdgcn_sched_barrier(0); \
    { /* din 4..7 */ \
        const float4 xb_ = ((const float4*)(xA + n_ * DIN))[1]; \
        const float4 yb_ = ((const float4*)(xB + n_ * DIN))[1]; \
        const float2 w4_ = wr_[32], w5_ = wr_[40], w6_ = wr_[48], w7_ = wr_[56]; \
        a_.x += xb_.x*w4_.x + xb_.y*w5_.x + xb_.z*w6_.x + xb_.w*w7_.x; \
        a_.y += xb_.x*w4_.y + xb_.y*w5_.y + xb_.z*w6_.y + xb_.w*w7_.y; \
        d_.x += yb_.x*w4_.x + yb_.y*w5_.x + yb_.z*w6_.x + yb_.w*w7_.x; \
        d_.y += yb_.x*w4_.y + yb_.y*w5_.y + yb_.z*w6_.y + yb_.w*w7_.y; \
    } \
    DA = a_; DB = d_; } \
    __builtin_amdgcn_sched_barrier(0);

    UHC(0, uA0, uB0)
    UHC(1, uA1, uB1)
    UHC(2, uA2, uB2)
    UHC(3, uA3, uB3)
    UHC(4, uA4, uB4)
    UHC(5, uA5, uB5)
    UHC(6, uA6, uB6)
    UHC(7, uA7, uB7)
    UHC(8, uA8, uB8)

    float2 pA, pB;
    float leA, leB;

    // ---- reduction helpers ----
    // p reduce: over the 8 gg-groups within a wave (lane bits 3..5).
#define PSTAGE(MK) { \
    pA.x += __shfl_xor(pA.x, MK); pA.y += __shfl_xor(pA.y, MK); \
    pB.x += __shfl_xor(pB.x, MK); pB.y += __shfl_xor(pB.y, MK); }

#define PRED_WRITE() { \
    PSTAGE(8) PSTAGE(16) PSTAGE(32) \
    if ((t & 63) < 8) { \
        ps[0][wave][u2+0] = pA.x; ps[0][wave][u2+1] = pA.y; \
        ps[1][wave][u2+0] = pB.x; ps[1][wave][u2+1] = pB.y; \
    } }

    // squash: threads 0..31 (wave 0). bi = batch, u = component.
#define SQUASH(USE_RED, WROUT) { \
    __syncthreads(); \
    if (t < 32) { \
        const int bi_ = t >> 4, u_ = t & 15; \
        float inv_; \
        if (USE_RED) { \
            float es_ = 0.f; \
            _Pragma("unroll") \
            for (int w_ = 0; w_ < 16; ++w_) es_ += redB[bi_][w_]; \
            inv_ = 8.0f / es_;               /* 8x lane overcount in le */ \
        } else { \
            inv_ = 1.0f / 1152.0f;           /* softmax(ones) is uniform */ \
        } \
        float s_ = 0.f; \
        _Pragma("unroll") \
        for (int w_ = 0; w_ < 16; ++w_) s_ += ps[bi_][w_][u_]; \
        s_ *= inv_; \
        float sq_ = s_ * s_; \
        sq_ += __shfl_xor(sq_, 1); sq_ += __shfl_xor(sq_, 2); \
        sq_ += __shfl_xor(sq_, 4); sq_ += __shfl_xor(sq_, 8); \
        const float sc_ = sq_ / ((1.0f + sq_) * sqrtf(sq_ + 1e-9f)); \
        const float v_ = sc_ * s_; \
        v_s[bi_][u_] = v_; \
        if (WROUT) out[((size_t)(b0 + bi_) * CAPS + c) * UDIM + u_] = v_; \
    } \
    __syncthreads(); }

    // b update: butterfly over the 8 owner lanes (u-thread bits 0..2).
#define BUP(K, UA, UB, INIT) { \
    float qa_ = UA.x*vA_.x + UA.y*vA_.y; \
    float qb_ = UB.x*vB_.x + UB.y*vB_.y; \
    qa_ += __shfl_xor(qa_, 1); qa_ += __shfl_xor(qa_, 2); qa_ += __shfl_xor(qa_, 4); \
    qb_ += __shfl_xor(qb_, 1); qb_ += __shfl_xor(qb_, 2); qb_ += __shfl_xor(qb_, 4); \
    if ((t & 7) == 0) { \
        const int n_ = gg + 128 * (K); \
        if (INIT) { b_s[0][n_] = 1.0f + qa_; b_s[1][n_] = 1.0f + qb_; } \
        else      { b_s[0][n_] += qa_;       b_s[1][n_] += qb_; } \
    } }

#define BUPD_ALL(INIT) { \
    const float2 vA_ = *(const float2*)(&v_s[0][u2]); \
    const float2 vB_ = *(const float2*)(&v_s[1][u2]); \
    BUP(0, uA0, uB0, INIT) BUP(1, uA1, uB1, INIT) \
    BUP(2, uA2, uB2, INIT) BUP(3, uA3, uB3, INIT) \
    BUP(4, uA4, uB4, INIT) BUP(5, uA5, uB5, INIT) \
    BUP(6, uA6, uB6, INIT) BUP(7, uA7, uB7, INIT) \
    BUP(8, uA8, uB8, INIT) \
    __syncthreads(); }

#define PADD(UA, UB) { \
    pA.x += UA.x; pA.y += UA.y; \
    pB.x += UB.x; pB.y += UB.y; }

#define ACCE(K, UA, UB) { \
    const float eA_ = expf(b_s[0][gg + 128*(K)]); \
    const float eB_ = expf(b_s[1][gg + 128*(K)]); \
    leA += eA_; leB += eB_; \
    pA.x += eA_*UA.x; pA.y += eA_*UA.y; \
    pB.x += eB_*UB.x; pB.y += eB_*UB.y; }

#define LERED_WRITE() { \
    leA += __shfl_xor(leA, 1);  leB += __shfl_xor(leB, 1); \
    leA += __shfl_xor(leA, 2);  leB += __shfl_xor(leB, 2); \
    leA += __shfl_xor(leA, 4);  leB += __shfl_xor(leB, 4); \
    leA += __shfl_xor(leA, 8);  leB += __shfl_xor(leB, 8); \
    leA += __shfl_xor(leA, 16); leB += __shfl_xor(leB, 16); \
    leA += __shfl_xor(leA, 32); leB += __shfl_xor(leB, 32); \
    if ((t & 63) == 0) { redB[0][wave] = leA; redB[1][wave] = leB; } }

    // ---- iteration 0: c is uniform 1/1152, no exp needed ----
    pA = uA0; pB = uB0;
    PADD(uA1, uB1) PADD(uA2, uB2) PADD(uA3, uB3) PADD(uA4, uB4)
    PADD(uA5, uB5) PADD(uA6, uB6) PADD(uA7, uB7) PADD(uA8, uB8)
    PRED_WRITE()
    SQUASH(0, 0)
    BUPD_ALL(1)            // b = 1 + u_hat . v0

    // ---- iteration 1 ----
    leA = 0.f; leB = 0.f;
    pA = make_float2(0.f, 0.f); pB = make_float2(0.f, 0.f);
    ACCE(0, uA0, uB0) ACCE(1, uA1, uB1) ACCE(2, uA2, uB2)
    ACCE(3, uA3, uB3) ACCE(4, uA4, uB4) ACCE(5, uA5, uB5)
    ACCE(6, uA6, uB6) ACCE(7, uA7, uB7) ACCE(8, uA8, uB8)
    LERED_WRITE()
    PRED_WRITE()
    SQUASH(1, 0)
    BUPD_ALL(0)            // b += u_hat . v1

    // ---- iteration 2 (writes out) ----
    leA = 0.f; leB = 0.f;
    pA = make_float2(0.f, 0.f); pB = make_float2(0.f, 0.f);
    ACCE(0, uA0, uB0) ACCE(1, uA1, uB1) ACCE(2, uA2, uB2)
    ACCE(3, uA3, uB3) ACCE(4, uA4, uB4) ACCE(5, uA5, uB5)
    ACCE(6, uA6, uB6) ACCE(7, uA7, uB7) ACCE(8, uA8, uB8)
    LERED_WRITE()
    PRED_WRITE()
    SQUASH(1, 1)
}

extern "C" void kernel_launch(void* const* d_in, const int* in_sizes, int n_in,
                              void* d_out, int out_size, void* d_ws, size_t ws_size,
                              hipStream_t stream) {
    const float* x = (const float*)d_in[0];   // (256, 1152, 8)
    const float* W = (const float*)d_in[1];   // (10, 1152, 8, 16)
    float* out = (float*)d_out;               // (256, 10, 16)
    capsule_routing_kernel<<<CAPS * (BATCH / 2), TPB, 0, stream>>>(x, W, out);
}

// Round 8
// 131.920 us; speedup vs baseline: 1.4694x; 1.4694x over previous
//
#include <hip/hip_runtime.h>
#include <math.h>

// Capsule dynamic routing, fully fused, 1-BATCH, LDS-lean: one block of 512
// threads per (b, c). B=256, C=10, N=1152, Din=8, U=16, 3 iters.
//
// Round-8. Allocator model (8 data points): ONLY TPB=512 + launch_bounds(512,1)
// allocates demand-sized registers without spilling (R0: 56 regs, R6: 100 regs,
// both WRITE~=output). Every other config (512,{2,4}), TPB=1024, waves_per_eu
// attr) imposed a sub-demand budget and spilled 25-130 MB of scratch.
// R0 (occ 42%, LDS-capped 3 blk/CU) == R6 (occ 22%, reg-capped) == ~90us:
// both latency-bound, perf ~ resident waves x per-wave efficiency.
// This round: R0's small live set (1-batch, 36 u_hat floats, ~64-75 regs)
// + R6's LDS diet (x direct from global, 4-lane broadcast; b_s in LDS;
// no x_s) -> ~5 KB LDS, nothing caps occupancy below 3-4 blocks/CU
// (75-100% theoretical) = ~2x R0's latency hiding at identical per-wave work.
//  * u_hat in 9 NAMED float4 regs (array form spills).
//  * UHC split in two din-halves with sched_barrier(0) to cap in-flight
//    loads (~4 W float4) and keep demand ~70 regs.
//  * iteration 0 peeled: softmax(ones) == 1/1152 exactly, no exp pass.
//  * c-major grid: 256 consecutive blocks share one c's 590 KB W slab
//    across XCD L2s.

#define BATCH 256
#define CAPS  10
#define NIN   1152
#define DIN   8
#define UDIM  16
#define TPB   512

__global__ __launch_bounds__(TPB, 1) void capsule_routing_kernel(
    const float* __restrict__ x,   // (B, N, Din)
    const float* __restrict__ W,   // (C, N, Din, U)
    float* __restrict__ out)       // (B, C, U)
{
    const int gblk = blockIdx.x;      // c-major for L2 W-locality
    const int c    = gblk >> 8;       // 0..9
    const int b    = gblk & 255;      // 0..255
    const int t    = threadIdx.x;     // 0..511
    const int ub   = (t & 3) << 2;    // u base: 0,4,8,12
    const int gg   = t >> 2;          // 0..127 (n residue)
    const int wave = t >> 6;          // 0..7

    __shared__ float b_s[NIN];          // routing logits (4.6 KB)
    __shared__ float redB[8];           // per-wave exp-sum partials
    __shared__ float ps[8][UDIM];       // per-wave partial s
    __shared__ float v_s[UDIM];         // squashed output

    const float* Wc = W + (size_t)c * (NIN * DIN * UDIM);
    const float* xb = x + (size_t)b * (NIN * DIN);

    // u_hat in 9 NAMED float4 registers (array form spills)
    float4 uh0,uh1,uh2,uh3,uh4,uh5,uh6,uh7,uh8;

#define UHC(K, DST) { \
    const int n_ = gg + 128 * (K); \
    const float4* wr_ = (const float4*)(Wc + n_ * (DIN * UDIM) + ub); \
    float4 a_; \
    { /* din 0..3 */ \
        const float4 xa_ = ((const float4*)(xb + n_ * DIN))[0]; \
        const float4 w0_ = wr_[0], w1_ = wr_[4], w2_ = wr_[8], w3_ = wr_[12]; \
        a_.x = xa_.x*w0_.x + xa_.y*w1_.x + xa_.z*w2_.x + xa_.w*w3_.x; \
        a_.y = xa_.x*w0_.y + xa_.y*w1_.y + xa_.z*w2_.y + xa_.w*w3_.y; \
        a_.z = xa_.x*w0_.z + xa_.y*w1_.z + xa_.z*w2_.z + xa_.w*w3_.z; \
        a_.w = xa_.x*w0_.w + xa_.y*w1_.w + xa_.z*w2_.w + xa_.w*w3_.w; \
    } \
    __builtin_amdgcn_sched_barrier(0); \
    { /* din 4..7 */ \
        const float4 xc_ = ((const float4*)(xb + n_ * DIN))[1]; \
        const float4 w4_ = wr_[16], w5_ = wr_[20], w6_ = wr_[24], w7_ = wr_[28]; \
        a_.x += xc_.x*w4_.x + xc_.y*w5_.x + xc_.z*w6_.x + xc_.w*w7_.x; \
        a_.y += xc_.x*w4_.y + xc_.y*w5_.y + xc_.z*w6_.y + xc_.w*w7_.y; \
        a_.z += xc_.x*w4_.z + xc_.y*w5_.z + xc_.z*w6_.z + xc_.w*w7_.z; \
        a_.w += xc_.x*w4_.w + xc_.y*w5_.w + xc_.z*w6_.w + xc_.w*w7_.w; \
    } \
    DST = a_; } \
    __builtin_amdgcn_sched_barrier(0);

    UHC(0, uh0)
    UHC(1, uh1)
    UHC(2, uh2)
    UHC(3, uh3)
    UHC(4, uh4)
    UHC(5, uh5)
    UHC(6, uh6)
    UHC(7, uh7)
    UHC(8, uh8)

    float4 p;
    float le;

    // ---- reduction helpers ----
#define PSTAGE(MK) { \
    p.x += __shfl_xor(p.x, MK); p.y += __shfl_xor(p.y, MK); \
    p.z += __shfl_xor(p.z, MK); p.w += __shfl_xor(p.w, MK); }

#define PRED_WRITE() { \
    PSTAGE(4) PSTAGE(8) PSTAGE(16) PSTAGE(32) \
    if ((t & 63) < 4) { \
        ps[wave][ub+0] = p.x; ps[wave][ub+1] = p.y; \
        ps[wave][ub+2] = p.z; ps[wave][ub+3] = p.w; \
    } }

    // squash on first 16 threads
#define SQUASH(USE_RED, WROUT) { \
    __syncthreads(); \
    if (t < UDIM) { \
        float inv_; \
        if (USE_RED) { \
            float es_ = 0.f; \
            es_ += redB[0]; es_ += redB[1]; es_ += redB[2]; es_ += redB[3]; \
            es_ += redB[4]; es_ += redB[5]; es_ += redB[6]; es_ += redB[7]; \
            inv_ = 4.0f / es_;               /* 4x lane overcount in le */ \
        } else { \
            inv_ = 1.0f / 1152.0f;           /* softmax(ones) is uniform */ \
        } \
        float s_ = 0.f; \
        s_ += ps[0][t]; s_ += ps[1][t]; s_ += ps[2][t]; s_ += ps[3][t]; \
        s_ += ps[4][t]; s_ += ps[5][t]; s_ += ps[6][t]; s_ += ps[7][t]; \
        s_ *= inv_; \
        float sq_ = s_ * s_; \
        sq_ += __shfl_xor(sq_, 1); sq_ += __shfl_xor(sq_, 2); \
        sq_ += __shfl_xor(sq_, 4); sq_ += __shfl_xor(sq_, 8); \
        const float sc_ = sq_ / ((1.0f + sq_) * sqrtf(sq_ + 1e-9f)); \
        const float v_ = sc_ * s_; \
        v_s[t] = v_; \
        if (WROUT) out[((size_t)b * CAPS + c) * UDIM + t] = v_; \
    } \
    __syncthreads(); }

    // b update: butterfly over the 4 owner lanes; owner lane writes LDS.
#define BUP(K, UH, INIT) { \
    float q_ = UH.x*v4_.x + UH.y*v4_.y + UH.z*v4_.z + UH.w*v4_.w; \
    q_ += __shfl_xor(q_, 1); q_ += __shfl_xor(q_, 2); \
    if ((t & 3) == 0) { \
        const int n_ = gg + 128 * (K); \
        if (INIT) b_s[n_] = 1.0f + q_; \
        else      b_s[n_] += q_; \
    } }

#define BUPD_ALL(INIT) { \
    const float4 v4_ = *(const float4*)(v_s + ub); \
    BUP(0, uh0, INIT) BUP(1, uh1, INIT) BUP(2, uh2, INIT) \
    BUP(3, uh3, INIT) BUP(4, uh4, INIT) BUP(5, uh5, INIT) \
    BUP(6, uh6, INIT) BUP(7, uh7, INIT) BUP(8, uh8, INIT) \
    __syncthreads(); }

#define PADD(UH) { \
    p.x += UH.x; p.y += UH.y; p.z += UH.z; p.w += UH.w; }

#define ACCE(K, UH) { \
    const float e_ = expf(b_s[gg + 128*(K)]); \
    le += e_; \
    p.x += e_*UH.x; p.y += e_*UH.y; p.z += e_*UH.z; p.w += e_*UH.w; }

#define LERED_WRITE() { \
    le += __shfl_xor(le, 1);  le += __shfl_xor(le, 2); \
    le += __shfl_xor(le, 4);  le += __shfl_xor(le, 8); \
    le += __shfl_xor(le, 16); le += __shfl_xor(le, 32); \
    if ((t & 63) == 0) redB[wave] = le; }

    // ---- iteration 0: c is uniform 1/1152, no exp needed ----
    p = uh0;
    PADD(uh1) PADD(uh2) PADD(uh3) PADD(uh4)
    PADD(uh5) PADD(uh6) PADD(uh7) PADD(uh8)
    PRED_WRITE()
    SQUASH(0, 0)
    BUPD_ALL(1)            // b = 1 + u_hat . v0

    // ---- iteration 1 ----
    le = 0.f;
    p = make_float4(0.f, 0.f, 0.f, 0.f);
    ACCE(0, uh0) ACCE(1, uh1) ACCE(2, uh2)
    ACCE(3, uh3) ACCE(4, uh4) ACCE(5, uh5)
    ACCE(6, uh6) ACCE(7, uh7) ACCE(8, uh8)
    LERED_WRITE()
    PRED_WRITE()
    SQUASH(1, 0)
    BUPD_ALL(0)            // b += u_hat . v1

    // ---- iteration 2 (writes out) ----
    le = 0.f;
    p = make_float4(0.f, 0.f, 0.f, 0.f);
    ACCE(0, uh0) ACCE(1, uh1) ACCE(2, uh2)
    ACCE(3, uh3) ACCE(4, uh4) ACCE(5, uh5)
    ACCE(6, uh6) ACCE(7, uh7) ACCE(8, uh8)
    LERED_WRITE()
    PRED_WRITE()
    SQUASH(1, 1)
}

extern "C" void kernel_launch(void* const* d_in, const int* in_sizes, int n_in,
                              void* d_out, int out_size, void* d_ws, size_t ws_size,
                              hipStream_t stream) {
    const float* x = (const float*)d_in[0];   // (256, 1152, 8)
    const float* W = (const float*)d_in[1];   // (10, 1152, 8, 16)
    float* out = (float*)d_out;               // (256, 10, 16)
    capsule_routing_kernel<<<BATCH * CAPS, TPB, 0, stream>>>(x, W, out);
}

// Round 10
// 125.694 us; speedup vs baseline: 1.5422x; 1.0495x over previous
//
#include <hip/hip_runtime.h>
#include <math.h>

// Capsule dynamic routing, fully fused, 1-BATCH, LDS-lean, MLP-maximized:
// one block of 512 threads per (b, c). B=256, C=10, N=1152, Din=8, U=16.
//
// Round-10 = round-9 resubmitted verbatim (round-9 bench died in container
// acquisition -- no data; same infra failure mode as round 5).
// Register model closed (9 rounds of evidence): rocprof VGPR_Count
// is a 2-reg granule (actual = 2x reported); launch_bounds(512,N) caps at
// 512/N actual; at (512,1)/TPB=512 the compiler always picks the ~112-actual
// tier = 4 waves/SIMD = 2 blocks/CU (~42% measured occ) regardless of LDS.
// R8 (no spill, occ 42%, dur ~90us) was still latency-bound in the UHC
// phase: din-split capped in-flight loads at 5/wave -> ~17 outstanding
// 64B lines/SIMD vs ~44 needed to saturate the per-CU L2 share (46us floor).
// THIS ROUND: merge the din-halves -- all 10 loads (8 W + 2 x) in flight
// per group, 9 stall points instead of 18. Demand +~20 regs, absorbed by
// the 128-actual tier without losing a block.
//  * u_hat in 9 NAMED float4 regs (array form spills).
//  * one sched_barrier(0) per UHC group (keeps groups from merging into a
//    register-ballooning mega-window -- R1's failure mode).
//  * b logits in LDS; x direct from global; iteration 0 peeled.

#define BATCH 256
#define CAPS  10
#define NIN   1152
#define DIN   8
#define UDIM  16
#define TPB   512

__global__ __launch_bounds__(TPB, 1) void capsule_routing_kernel(
    const float* __restrict__ x,   // (B, N, Din)
    const float* __restrict__ W,   // (C, N, Din, U)
    float* __restrict__ out)       // (B, C, U)
{
    const int gblk = blockIdx.x;      // c-major for L2 W-locality
    const int c    = gblk >> 8;       // 0..9
    const int b    = gblk & 255;      // 0..255
    const int t    = threadIdx.x;     // 0..511
    const int ub   = (t & 3) << 2;    // u base: 0,4,8,12
    const int gg   = t >> 2;          // 0..127 (n residue)
    const int wave = t >> 6;          // 0..7

    __shared__ float b_s[NIN];          // routing logits (4.6 KB)
    __shared__ float redB[8];           // per-wave exp-sum partials
    __shared__ float ps[8][UDIM];       // per-wave partial s
    __shared__ float v_s[UDIM];         // squashed output

    const float* Wc = W + (size_t)c * (NIN * DIN * UDIM);
    const float* xb = x + (size_t)b * (NIN * DIN);

    // u_hat in 9 NAMED float4 registers (array form spills)
    float4 uh0,uh1,uh2,uh3,uh4,uh5,uh6,uh7,uh8;

    // All 10 loads of a group (8 W float4 + 2 x float4) issue together:
    // maximal per-wave MLP; one latency wait per group instead of two.
#define UHC(K, DST) { \
    const int n_ = gg + 128 * (K); \
    const float4* wr_ = (const float4*)(Wc + n_ * (DIN * UDIM) + ub); \
    const float4 xa_ = ((const float4*)(xb + n_ * DIN))[0]; \
    const float4 xc_ = ((const float4*)(xb + n_ * DIN))[1]; \
    const float4 w0_ = wr_[0],  w1_ = wr_[4],  w2_ = wr_[8],  w3_ = wr_[12]; \
    const float4 w4_ = wr_[16], w5_ = wr_[20], w6_ = wr_[24], w7_ = wr_[28]; \
    float4 a_; \
    a_.x = xa_.x*w0_.x + xa_.y*w1_.x + xa_.z*w2_.x + xa_.w*w3_.x; \
    a_.y = xa_.x*w0_.y + xa_.y*w1_.y + xa_.z*w2_.y + xa_.w*w3_.y; \
    a_.z = xa_.x*w0_.z + xa_.y*w1_.z + xa_.z*w2_.z + xa_.w*w3_.z; \
    a_.w = xa_.x*w0_.w + xa_.y*w1_.w + xa_.z*w2_.w + xa_.w*w3_.w; \
    a_.x += xc_.x*w4_.x + xc_.y*w5_.x + xc_.z*w6_.x + xc_.w*w7_.x; \
    a_.y += xc_.x*w4_.y + xc_.y*w5_.y + xc_.z*w6_.y + xc_.w*w7_.y; \
    a_.z += xc_.x*w4_.z + xc_.y*w5_.z + xc_.z*w6_.z + xc_.w*w7_.z; \
    a_.w += xc_.x*w4_.w + xc_.y*w5_.w + xc_.z*w6_.w + xc_.w*w7_.w; \
    DST = a_; } \
    __builtin_amdgcn_sched_barrier(0);

    UHC(0, uh0)
    UHC(1, uh1)
    UHC(2, uh2)
    UHC(3, uh3)
    UHC(4, uh4)
    UHC(5, uh5)
    UHC(6, uh6)
    UHC(7, uh7)
    UHC(8, uh8)

    float4 p;
    float le;

    // ---- reduction helpers ----
#define PSTAGE(MK) { \
    p.x += __shfl_xor(p.x, MK); p.y += __shfl_xor(p.y, MK); \
    p.z += __shfl_xor(p.z, MK); p.w += __shfl_xor(p.w, MK); }

#define PRED_WRITE() { \
    PSTAGE(4) PSTAGE(8) PSTAGE(16) PSTAGE(32) \
    if ((t & 63) < 4) { \
        ps[wave][ub+0] = p.x; ps[wave][ub+1] = p.y; \
        ps[wave][ub+2] = p.z; ps[wave][ub+3] = p.w; \
    } }

    // squash on first 16 threads
#define SQUASH(USE_RED, WROUT) { \
    __syncthreads(); \
    if (t < UDIM) { \
        float inv_; \
        if (USE_RED) { \
            float es_ = 0.f; \
            es_ += redB[0]; es_ += redB[1]; es_ += redB[2]; es_ += redB[3]; \
            es_ += redB[4]; es_ += redB[5]; es_ += redB[6]; es_ += redB[7]; \
            inv_ = 4.0f / es_;               /* 4x lane overcount in le */ \
        } else { \
            inv_ = 1.0f / 1152.0f;           /* softmax(ones) is uniform */ \
        } \
        float s_ = 0.f; \
        s_ += ps[0][t]; s_ += ps[1][t]; s_ += ps[2][t]; s_ += ps[3][t]; \
        s_ += ps[4][t]; s_ += ps[5][t]; s_ += ps[6][t]; s_ += ps[7][t]; \
        s_ *= inv_; \
        float sq_ = s_ * s_; \
        sq_ += __shfl_xor(sq_, 1); sq_ += __shfl_xor(sq_, 2); \
        sq_ += __shfl_xor(sq_, 4); sq_ += __shfl_xor(sq_, 8); \
        const float sc_ = sq_ / ((1.0f + sq_) * sqrtf(sq_ + 1e-9f)); \
        const float v_ = sc_ * s_; \
        v_s[t] = v_; \
        if (WROUT) out[((size_t)b * CAPS + c) * UDIM + t] = v_; \
    } \
    __syncthreads(); }

    // b update: butterfly over the 4 owner lanes; owner lane writes LDS.
#define BUP(K, UH, INIT) { \
    float q_ = UH.x*v4_.x + UH.y*v4_.y + UH.z*v4_.z + UH.w*v4_.w; \
    q_ += __shfl_xor(q_, 1); q_ += __shfl_xor(q_, 2); \
    if ((t & 3) == 0) { \
        const int n_ = gg + 128 * (K); \
        if (INIT) b_s[n_] = 1.0f + q_; \
        else      b_s[n_] += q_; \
    } }

#define BUPD_ALL(INIT) { \
    const float4 v4_ = *(const float4*)(v_s + ub); \
    BUP(0, uh0, INIT) BUP(1, uh1, INIT) BUP(2, uh2, INIT) \
    BUP(3, uh3, INIT) BUP(4, uh4, INIT) BUP(5, uh5, INIT) \
    BUP(6, uh6, INIT) BUP(7, uh7, INIT) BUP(8, uh8, INIT) \
    __syncthreads(); }

#define PADD(UH) { \
    p.x += UH.x; p.y += UH.y; p.z += UH.z; p.w += UH.w; }

#define ACCE(K, UH) { \
    const float e_ = expf(b_s[gg + 128*(K)]); \
    le += e_; \
    p.x += e_*UH.x; p.y += e_*UH.y; p.z += e_*UH.z; p.w += e_*UH.w; }

#define LERED_WRITE() { \
    le += __shfl_xor(le, 1);  le += __shfl_xor(le, 2); \
    le += __shfl_xor(le, 4);  le += __shfl_xor(le, 8); \
    le += __shfl_xor(le, 16); le += __shfl_xor(le, 32); \
    if ((t & 63) == 0) redB[wave] = le; }

    // ---- iteration 0: c is uniform 1/1152, no exp needed ----
    p = uh0;
    PADD(uh1) PADD(uh2) PADD(uh3) PADD(uh4)
    PADD(uh5) PADD(uh6) PADD(uh7) PADD(uh8)
    PRED_WRITE()
    SQUASH(0, 0)
    BUPD_ALL(1)            // b = 1 + u_hat . v0

    // ---- iteration 1 ----
    le = 0.f;
    p = make_float4(0.f, 0.f, 0.f, 0.f);
    ACCE(0, uh0) ACCE(1, uh1) ACCE(2, uh2)
    ACCE(3, uh3) ACCE(4, uh4) ACCE(5, uh5)
    ACCE(6, uh6) ACCE(7, uh7) ACCE(8, uh8)
    LERED_WRITE()
    PRED_WRITE()
    SQUASH(1, 0)
    BUPD_ALL(0)            // b += u_hat . v1

    // ---- iteration 2 (writes out) ----
    le = 0.f;
    p = make_float4(0.f, 0.f, 0.f, 0.f);
    ACCE(0, uh0) ACCE(1, uh1) ACCE(2, uh2)
    ACCE(3, uh3) ACCE(4, uh4) ACCE(5, uh5)
    ACCE(6, uh6) ACCE(7, uh7) ACCE(8, uh8)
    LERED_WRITE()
    PRED_WRITE()
    SQUASH(1, 1)
}

extern "C" void kernel_launch(void* const* d_in, const int* in_sizes, int n_in,
                              void* d_out, int out_size, void* d_ws, size_t ws_size,
                              hipStream_t stream) {
    const float* x = (const float*)d_in[0];   // (256, 1152, 8)
    const float* W = (const float*)d_in[1];   // (10, 1152, 8, 16)
    float* out = (float*)d_out;               // (256, 10, 16)
    capsule_routing_kernel<<<BATCH * CAPS, TPB, 0, stream>>>(x, W, out);
}